// Round 10
// baseline (477.815 us; speedup 1.0000x reference)
//
#include <hip/hip_runtime.h>
#include <math.h>

#define TLEN (1 << 20)
#define CH 8               // hscan outputs per thread
#define WU 24              // warm-up steps (0.26^24 ~ 1e-14 << half-ulp: bit-exact)
#define SB 32              // reset-chain sub-chunk
#define NSB (TLEN / SB)    // 32768 sub-chunks
#define SCB 256            // maps per scan segment (= BLK)
#define NSCB (NSB / SCB)   // 128 scan segments
#define GRID 512           // co-resident: capacity 1024 via __launch_bounds__(256,4)
#define BLK 256
#define NTHR (GRID * BLK)  // 131072 threads
#define THRESH 1e-4f
#define IDMAP 0x00FAC688u  // packed identity map: entry g -> g (3 bits each)

#pragma clang fp contract(off)

// software grid barrier (cg grid.sync mechanics, graph-capture-safe):
// device-scope arrival atomic + leader spin + agent fences. ctr zeroed per call.
__device__ __forceinline__ void gridbar(unsigned int* ctr) {
    __threadfence();                       // release: make my writes visible
    __syncthreads();
    if (threadIdx.x == 0) {
        __hip_atomic_fetch_add(ctr, 1u, __ATOMIC_ACQ_REL, __HIP_MEMORY_SCOPE_AGENT);
        while (__hip_atomic_load(ctr, __ATOMIC_ACQUIRE, __HIP_MEMORY_SCOPE_AGENT) < GRID) {
            __builtin_amdgcn_s_sleep(8);
        }
    }
    __syncthreads();
    __threadfence();                       // acquire: invalidate stale cache lines
}

// One persistent kernel, 5 phases, 4 grid barriers. Every phase body is the
// round-8 PROVEN component verbatim (re-indexed grid-stride); all decay-chain
// arithmetic reads the single Z source (bit-identical across phases).
__global__ void __launch_bounds__(256, 4) k_all(const float* __restrict__ P,
                                                const float* __restrict__ X,
                                                float* __restrict__ Z,
                                                unsigned int* __restrict__ tab32,
                                                unsigned int* __restrict__ L32,
                                                unsigned int* __restrict__ BT,
                                                unsigned int* __restrict__ age,
                                                unsigned int* __restrict__ ctrs,
                                                float* __restrict__ Jout,
                                                float* __restrict__ Hout) {
#pragma clang fp contract(off)
    __shared__ float sc[4];
    __shared__ unsigned int buf[2][SCB];
    __shared__ unsigned int sBT[NSCB];
    int t = threadIdx.x;
    int tid = blockIdx.x * BLK + t;

    if (t == 0) {
        float tw1 = (float)tanh((double)P[0]);
        float tw2 = (float)tanh((double)P[1]);
        sc[0] = tw1; sc[1] = tw2; sc[2] = P[2]; sc[3] = P[3];
    }
    __syncthreads();
    float w1 = sc[0], w2 = sc[1], w3 = sc[2], w4 = sc[3];
    float w42 = 2.0f * w4;
    float dt1 = 1.0f - w1 * w1;
    float dt2 = 1.0f - w2 * w2;
    float d2t1 = (-2.0f * w1) * dt1;
    float d2t2 = (-2.0f * w2) * dt2;

    // ---- P1: hscan (round-8 proven body; CH=8, WU=24, 131072 threads) ----
    {
        long o = (long)tid * CH;
        long b = o - WU; if (b < 0) b = 0;
        long tend = o + CH - 1; if (tend > (long)TLEN - 1) tend = (long)TLEN - 1;
        float h = 0.0f;
        if (o == 0) Z[0] = 0.0f;
        for (long tt = b; tt < tend; ++tt) {
            float x = X[tt];
            float t1 = w1 * x;
            float t2 = w2 * h;
            float s1 = t1 + t2;
            float t3 = (w3 * x) * x;
            float s2 = s1 + t3;
            float t4 = (w4 * h) * h;
            h = s2 + t4;
            if (tt + 1 >= o) Z[tt + 1] = h;
        }
    }
    gridbar(ctrs + 0);

    // ---- P2: tables (round-5/8 proven body: one gap-chain per thread, reads Z;
    //           grid-stride x2, stride multiple of 8 keeps shfl groups aligned) ----
    for (long tt = tid; tt < (long)(NSB - 1) * 8; tt += NTHR) {
        int i = (int)(tt >> 3);
        int g = (int)(tt & 7);
        long start = (long)i * SB - g; if (start < 0) start = 0;
        long end = (long)(i + 1) * SB;
        float d = 1.0f;
        long last = start;
        for (long m = start + 1; m <= end; ++m) {
            float a = w2 + w42 * Z[m - 1];
            d = d * fabsf(a);
            if (d < THRESH) { last = m; d = 1.0f; }
        }
        long delta = end - last; if (delta > 7) delta = 7;   // provably never clamps
        unsigned int v = (unsigned int)delta << (3 * g);
        v |= __shfl_xor(v, 1);
        v |= __shfl_xor(v, 2);
        v |= __shfl_xor(v, 4);
        if (g == 0) tab32[i] = v;
    }
    gridbar(ctrs + 16);

    // ---- P3: per-segment Hillis-Steele scan (proven body; SCB=256, 128 blocks) ----
    if (blockIdx.x < NSCB) {
        long gi = (long)blockIdx.x * SCB + t;
        buf[0][t] = (gi < NSB - 1) ? tab32[gi] : IDMAP;
        __syncthreads();
        int cur = 0;
        for (int off = 1; off < SCB; off <<= 1) {
            unsigned int hi = buf[cur][t];
            unsigned int r;
            if (t >= off) {
                unsigned int lo = buf[cur][t - off];
                r = 0;
#pragma unroll
                for (int g = 0; g < 8; ++g) {
                    unsigned int lg = (lo >> (3 * g)) & 7u;
                    r |= ((hi >> (3 * lg)) & 7u) << (3 * g);
                }
            } else {
                r = hi;
            }
            buf[cur ^ 1][t] = r;
            __syncthreads();
            cur ^= 1;
        }
        L32[gi] = buf[cur][t];
        if (t == SCB - 1) BT[blockIdx.x] = buf[cur][t];
    }
    gridbar(ctrs + 32);

    // ---- P4: age (round-8 proven body; sBT serial compose, SCB=256 -> >>8) ----
    if (t < NSCB) sBT[t] = BT[t];
    __syncthreads();
    if (tid < NSB) {
        int i = tid;
        int e = 0;
        if (i > 0) {
            int b = (i - 1) >> 8;            // / SCB
            unsigned int g = 0;
            for (int k = 0; k < b; ++k) g = (sBT[k] >> (3 * g)) & 7u;   // g0[b]
            e = (int)((L32[i - 1] >> (3 * g)) & 7u);
        }
        long ci = (long)i * SB;
        long r = ci - e;
        float d = 1.0f;
        long last = r;
        for (long m = r + 1; m <= ci; ++m) {          // advance to sub-chunk start
            float a = w2 + w42 * Z[m - 1];
            d = d * fabsf(a);
            if (d < THRESH) { last = m; d = 1.0f; }
        }
        unsigned int w[8];
        unsigned int cw = (unsigned int)(ci - last);  // age at sub-chunk start
        int slot = 1, wi = 0;
#pragma unroll
        for (int k = 1; k < SB; ++k) {
            long m = ci + k;
            float a = w2 + w42 * Z[m - 1];
            d = d * fabsf(a);
            if (d < THRESH) { last = m; d = 1.0f; }
            cw |= ((unsigned int)(m - last)) << (8 * slot);
            if (++slot == 4) { w[wi++] = cw; cw = 0u; slot = 0; }
        }
        uint4* dst = (uint4*)age + (long)i * 2;
        dst[0] = make_uint4(w[0], w[1], w[2], w[3]);
        dst[1] = make_uint4(w[4], w[5], w[6], w[7]);
    }
    gridbar(ctrs + 48);

    // ---- P5: jh (round-8 proven body verbatim; grid-stride x4) ----
    const unsigned short* age2 = (const unsigned short*)age;
    for (long i2 = tid; i2 < TLEN / 2; i2 += NTHR) {
        long q0 = 2 * i2;
        unsigned int u = age2[i2];
        int a0 = (int)(u & 0xffu);
        int a1 = (int)(u >> 8);
        float J0 = 0, J1 = 0, J2 = 0, J3 = 0;
        float H00 = 0, H01 = 0, H03 = 0, H11 = 0, H12 = 0, H13 = 0, H23 = 0, H33 = 0;

#define JH_SIMPLE(mm) {                                                        \
        float x = X[(mm) - 1];                                                 \
        float h = Z[(mm) - 1];                                                 \
        H00 = x * d2t1; H11 = h * d2t2;                                        \
        J0 = x * dt1; J1 = h * dt2; J2 = x * x; J3 = h * h;                    \
    }

#define JH_STEP(mm)  {                                                         \
        float x = X[(mm) - 1];                                                 \
        float h = Z[(mm) - 1];                                                 \
        float av = w2 + w42 * h;                                               \
        float g3 = 2.0f * h;                                                   \
        float g1J0 = dt2 * J0, g1J1 = dt2 * J1, g1J2 = dt2 * J2, g1J3 = dt2 * J3; \
        float g3J0 = g3 * J0, g3J1 = g3 * J1, g3J2 = g3 * J2, g3J3 = g3 * J3;  \
        float n00 = (x * d2t1) + av * H00;                                     \
        float n01 = g1J0 + av * H01;                                           \
        float n03 = g3J0 + av * H03;                                           \
        float n11 = (((h * d2t2) + g1J1) + g1J1) + av * H11;                   \
        float n12 = g1J2 + av * H12;                                           \
        float n13 = (g1J3 + g3J1) + av * H13;                                  \
        float n23 = g3J2 + av * H23;                                           \
        float n33 = (g3J3 + g3J3) + av * H33;                                  \
        H00 = n00; H01 = n01; H03 = n03; H11 = n11;                            \
        H12 = n12; H13 = n13; H23 = n23; H33 = n33;                            \
        J0 = (x * dt1) + av * J0;                                              \
        J1 = (h * dt2) + av * J1;                                              \
        J2 = (x * x) + av * J2;                                                \
        J3 = (h * h) + av * J3;                                                \
    }

#define JH_EMIT(qq)  {                                                         \
        *((float4*)(Jout + 4 * (qq))) = make_float4(J0, J1, J2, J3);           \
        float4* Hp = (float4*)(Hout + 16 * (qq));                              \
        Hp[0] = make_float4(H00, H01, 0.0f, H03);                              \
        Hp[1] = make_float4(H01, H11, H12, H13);                               \
        Hp[2] = make_float4(0.0f, H12, 0.0f, H23);                             \
        Hp[3] = make_float4(H03, H13, H23, H33);                               \
    }

        if (a0 > 0) {
            long m0 = q0 - a0 + 1;
            JH_SIMPLE(m0);
            for (long m = m0 + 1; m <= q0; ++m) JH_STEP(m);
        }
        JH_EMIT(q0);
        if (a1 == 0) {
            long q1 = q0 + 1;
            float4 z4 = make_float4(0.f, 0.f, 0.f, 0.f);
            *((float4*)(Jout + 4 * q1)) = z4;
            float4* Hp = (float4*)(Hout + 16 * q1);
            Hp[0] = z4; Hp[1] = z4; Hp[2] = z4; Hp[3] = z4;
        } else {
            if (a1 == 1) { JH_SIMPLE(q0 + 1); }
            else         { JH_STEP(q0 + 1); }
            JH_EMIT(q0 + 1);
        }
#undef JH_SIMPLE
#undef JH_STEP
#undef JH_EMIT
    }
}

extern "C" void kernel_launch(void* const* d_in, const int* in_sizes, int n_in,
                              void* d_out, int out_size, void* d_ws, size_t ws_size,
                              hipStream_t stream) {
    const float* X = (const float*)d_in[0];
    const float* P = (const float*)d_in[1];
    float* out = (float*)d_out;
    float* Z = out;                       // [T]
    float* Jout = out + (long)TLEN;       // [T,4]
    float* Hout = out + 5l * TLEN;        // [T,4,4]

    char* ws = (char*)d_ws;
    unsigned int* ctrs = (unsigned int*)ws;                        // @0, 256 B (4x64B)
    unsigned int* BT = (unsigned int*)(ws + 256);                  // 128 dwords
    unsigned int* tab32 = (unsigned int*)(ws + 1024);              // 128 KB
    unsigned int* L32 = (unsigned int*)(ws + 1024 + (size_t)NSB * 4);      // 128 KB
    unsigned int* age = (unsigned int*)(ws + 1024 + 2 * (size_t)NSB * 4);  // 1 MB

    hipMemsetAsync(ctrs, 0, 256, stream);   // zero barrier counters every call
    hipLaunchKernelGGL(k_all, dim3(GRID), dim3(BLK), 0, stream,
                       P, X, Z, tab32, L32, BT, age, ctrs, Jout, Hout);
}

// Round 11
// 66.364 us; speedup vs baseline: 7.1999x; 7.1999x over previous
//
#include <hip/hip_runtime.h>
#include <math.h>

#define TLEN (1 << 20)
#define SB 32              // reset-chain sub-chunk
#define NSB (TLEN / SB)    // 32768 sub-chunks
#define SCB 512            // maps per scan block
#define NSCB (NSB / SCB)   // 64 scan blocks
#define THRESH 1e-4f
#define IDMAP 0x00FAC688u  // packed identity map: entry g -> g (3 bits each)

#define WWORDS (SCB * SB + 8)      // 16392 staged Z words (8 lead words)
#define WPAD(i) ((i) + ((i) >> 5)) // +1 word per 32: kills stride-32 bank conflicts
#define LDSW WPAD(WWORDS)

#pragma clang fp contract(off)

// consts layout: 0:w1 1:w2 2:w3 3:w4 4:dt1 5:dt2 6:d2t1 7:d2t2 8:2*w4

// K1: h (=Z). Fully-unrolled 31-step chain, float4 loads/stores (bit-identical
// arithmetic to the proven scalar body; only access width changed). j<3 scalar.
__global__ void __launch_bounds__(256) k_hscan(const float* __restrict__ P,
                                               const float* __restrict__ X,
                                               float* __restrict__ c,
                                               float* __restrict__ Z) {
#pragma clang fp contract(off)
    __shared__ float sc[4];
    if (threadIdx.x == 0) {
        float w1 = (float)tanh((double)P[0]);
        float w2 = (float)tanh((double)P[1]);
        sc[0] = w1; sc[1] = w2; sc[2] = P[2]; sc[3] = P[3];
        if (blockIdx.x == 0) {
            float dt1 = 1.0f - w1 * w1;
            float dt2 = 1.0f - w2 * w2;
            c[0] = w1; c[1] = w2; c[2] = P[2]; c[3] = P[3];
            c[4] = dt1; c[5] = dt2;
            c[6] = (-2.0f * w1) * dt1; c[7] = (-2.0f * w2) * dt2;
            c[8] = 2.0f * P[3];
        }
    }
    __syncthreads();
    float w1 = sc[0], w2 = sc[1], w3 = sc[2], w4 = sc[3];
    long j = blockIdx.x * (long)blockDim.x + threadIdx.x;
    long o = j * 8;
    if (j >= 3) {
        const float4* xp = (const float4*)(X + o - 24);
        float xa[32];
#pragma unroll
        for (int q = 0; q < 8; ++q) {
            float4 v = xp[q];
            xa[4 * q + 0] = v.x; xa[4 * q + 1] = v.y;
            xa[4 * q + 2] = v.z; xa[4 * q + 3] = v.w;
        }
        float h = 0.0f;
        float out[8];
#pragma unroll
        for (int p = 0; p < 31; ++p) {
            float x = xa[p];
            float t1 = w1 * x;
            float t2 = w2 * h;
            float s1 = t1 + t2;
            float t3 = (w3 * x) * x;
            float s2 = s1 + t3;
            float t4 = (w4 * h) * h;
            h = s2 + t4;
            if (p >= 23) out[p - 23] = h;
        }
        *(float4*)(Z + o) = make_float4(out[0], out[1], out[2], out[3]);
        *(float4*)(Z + o + 4) = make_float4(out[4], out[5], out[6], out[7]);
    } else {
        long b = o - 24; if (b < 0) b = 0;
        long tend = o + 7;
        float h = 0.0f;
        if (o == 0) Z[0] = 0.0f;
        for (long t = b; t < tend; ++t) {
            float x = X[t];
            float t1 = w1 * x;
            float t2 = w2 * h;
            float s1 = t1 + t2;
            float t3 = (w3 * x) * x;
            float s2 = s1 + t3;
            float t4 = (w4 * h) * h;
            h = s2 + t4;
            if (t + 1 >= o) Z[t + 1] = h;
        }
    }
}

// K2: fused tables + scan (round-8 PROVEN, verbatim).
__global__ void __launch_bounds__(512) k_tabscan(const float* __restrict__ c,
                                                 const float* __restrict__ Z,
                                                 unsigned int* __restrict__ L32,
                                                 unsigned int* __restrict__ BT) {
#pragma clang fp contract(off)
    __shared__ float zw[LDSW];
    __shared__ unsigned int buf[2][SCB];
    int t = threadIdx.x;
    int b = blockIdx.x;
    long wo = (long)b * (SCB * SB) - 8;    // Z index of raw window word 0
    for (int v = 0; v < 9; ++v) {
        int q = v * 512 + t;
        if (q < WWORDS / 4) {              // 4098 float4s
            long zi = wo + 4l * q;
            float4 val = make_float4(0.f, 0.f, 0.f, 0.f);
            if (zi >= 0) val = *(const float4*)(Z + zi);
            int r0 = 4 * q;
            zw[WPAD(r0 + 0)] = val.x;
            zw[WPAD(r0 + 1)] = val.y;
            zw[WPAD(r0 + 2)] = val.z;
            zw[WPAD(r0 + 3)] = val.w;
        }
    }
    __syncthreads();
    float w2 = c[1], w42 = c[8];
    long gi = (long)b * SCB + t;
    unsigned int m32;
    if (gi < NSB - 1) {
        int rbase = t * 32 + 8;            // raw index of rel=0 (pos = gi*32)
        float d[8]; int last[8];
#pragma unroll
        for (int g = 0; g < 8; ++g) { d[g] = 1.0f; last[g] = -g; }
        if (gi == 0) {
#pragma unroll
            for (int g = 0; g < 8; ++g) last[g] = 0;   // all chains start at 0
            for (int k = 0; k < 32; ++k) {
                float fa = fabsf(w2 + w42 * zw[WPAD(rbase + k)]);
#pragma unroll
                for (int g = 0; g < 8; ++g) {
                    d[g] = d[g] * fa;
                    if (d[g] < THRESH) { last[g] = k + 1; d[g] = 1.0f; }
                }
            }
        } else {
#pragma unroll
            for (int p = 0; p < 7; ++p) {  // rel = p-7; chain g live iff g >= 7-p
                float fa = fabsf(w2 + w42 * zw[WPAD(rbase + p - 7)]);
#pragma unroll
                for (int g = 7 - p; g < 8; ++g) {
                    d[g] = d[g] * fa;
                    if (d[g] < THRESH) { last[g] = p - 6; d[g] = 1.0f; }
                }
            }
            for (int k = 0; k < 32; ++k) {
                float fa = fabsf(w2 + w42 * zw[WPAD(rbase + k)]);
#pragma unroll
                for (int g = 0; g < 8; ++g) {
                    d[g] = d[g] * fa;
                    if (d[g] < THRESH) { last[g] = k + 1; d[g] = 1.0f; }
                }
            }
        }
        m32 = 0;
#pragma unroll
        for (int g = 0; g < 8; ++g) {
            int delta = 32 - last[g]; if (delta > 7) delta = 7;  // provably never clamps
            m32 |= (unsigned int)delta << (3 * g);
        }
    } else {
        m32 = IDMAP;
    }
    buf[0][t] = m32;
    __syncthreads();
    int cur = 0;
    for (int off = 1; off < SCB; off <<= 1) {
        unsigned int hi = buf[cur][t];
        unsigned int r;
        if (t >= off) {
            unsigned int lo = buf[cur][t - off];
            r = 0;
#pragma unroll
            for (int g = 0; g < 8; ++g) {
                unsigned int lg = (lo >> (3 * g)) & 7u;
                r |= ((hi >> (3 * lg)) & 7u) << (3 * g);
            }
        } else {
            r = hi;
        }
        buf[cur ^ 1][t] = r;
        __syncthreads();
        cur ^= 1;
    }
    L32[gi] = buf[cur][t];
    if (t == SCB - 1) BT[b] = buf[cur][t];
}

// K3: age (round-8 PROVEN, verbatim).
__global__ void __launch_bounds__(256) k_age(const float* __restrict__ c,
                                             const float* __restrict__ Z,
                                             const unsigned int* __restrict__ L32,
                                             const unsigned int* __restrict__ BT,
                                             unsigned int* __restrict__ age) {
#pragma clang fp contract(off)
    __shared__ unsigned int sBT[NSCB];
    int t = threadIdx.x;
    if (t < NSCB) sBT[t] = BT[t];
    __syncthreads();
    int i = blockIdx.x * blockDim.x + t;
    if (i >= NSB) return;
    float w2 = c[1], w42 = c[8];
    int e = 0;
    if (i > 0) {
        int b = (i - 1) >> 9;            // / SCB
        unsigned int g = 0;
        for (int k = 0; k < b; ++k) g = (sBT[k] >> (3 * g)) & 7u;   // g0[b]
        e = (int)((L32[i - 1] >> (3 * g)) & 7u);
    }
    long ci = (long)i * SB;
    long r = ci - e;
    float d = 1.0f;
    long last = r;
    for (long m = r + 1; m <= ci; ++m) {          // advance to sub-chunk start
        float a = w2 + w42 * Z[m - 1];
        d = d * fabsf(a);
        if (d < THRESH) { last = m; d = 1.0f; }
    }
    unsigned int w[8];
    unsigned int cw = (unsigned int)(ci - last);  // age at sub-chunk start
    int slot = 1, wi = 0;
#pragma unroll
    for (int k = 1; k < SB; ++k) {
        long m = ci + k;
        float a = w2 + w42 * Z[m - 1];
        d = d * fabsf(a);
        if (d < THRESH) { last = m; d = 1.0f; }
        cw |= ((unsigned int)(m - last)) << (8 * slot);
        if (++slot == 4) { w[wi++] = cw; cw = 0u; slot = 0; }
    }
    uint4* dst = (uint4*)age + (long)i * 2;
    dst[0] = make_uint4(w[0], w[1], w[2], w[3]);
    dst[1] = make_uint4(w[4], w[5], w[6], w[7]);
}

// K4: rebuild J,H; 4 consecutive outputs per thread share the warm-back chain.
// Reset handling per output: age==0 -> zeros (+zero regs), age==1 -> fresh
// SIMPLE (explicitly zeroes all H terms), age>=2 -> STEP. Induction on packed
// ages keeps register state exact; all 4 outputs lie in one SB=32 sub-chunk.
__global__ void __launch_bounds__(256) k_jh(const float* __restrict__ X,
                                            const float* __restrict__ Z,
                                            const float* __restrict__ c,
                                            const unsigned int* __restrict__ age4,
                                            float* __restrict__ Jout,
                                            float* __restrict__ Hout) {
#pragma clang fp contract(off)
    long i4 = blockIdx.x * (long)blockDim.x + threadIdx.x;
    if (i4 >= TLEN / 4) return;
    long q0 = 4 * i4;
    float w2 = c[1], dt1 = c[4], dt2 = c[5], d2t1 = c[6], d2t2 = c[7], w42 = c[8];
    unsigned int u = age4[i4];
    int a0 = (int)(u & 0xffu);
    float J0 = 0, J1 = 0, J2 = 0, J3 = 0;
    float H00 = 0, H01 = 0, H03 = 0, H11 = 0, H12 = 0, H13 = 0, H23 = 0, H33 = 0;

#define JH_SIMPLE(mm) {                                                        \
        float x = X[(mm) - 1];                                                 \
        float h = Z[(mm) - 1];                                                 \
        H00 = x * d2t1; H11 = h * d2t2;                                        \
        H01 = 0.0f; H03 = 0.0f; H12 = 0.0f; H13 = 0.0f; H23 = 0.0f; H33 = 0.0f;\
        J0 = x * dt1; J1 = h * dt2; J2 = x * x; J3 = h * h;                    \
    }

#define JH_STEP(mm)  {                                                         \
        float x = X[(mm) - 1];                                                 \
        float h = Z[(mm) - 1];                                                 \
        float av = w2 + w42 * h;                                               \
        float g3 = 2.0f * h;                                                   \
        float g1J0 = dt2 * J0, g1J1 = dt2 * J1, g1J2 = dt2 * J2, g1J3 = dt2 * J3; \
        float g3J0 = g3 * J0, g3J1 = g3 * J1, g3J2 = g3 * J2, g3J3 = g3 * J3;  \
        float n00 = (x * d2t1) + av * H00;                                     \
        float n01 = g1J0 + av * H01;                                           \
        float n03 = g3J0 + av * H03;                                           \
        float n11 = (((h * d2t2) + g1J1) + g1J1) + av * H11;                   \
        float n12 = g1J2 + av * H12;                                           \
        float n13 = (g1J3 + g3J1) + av * H13;                                  \
        float n23 = g3J2 + av * H23;                                           \
        float n33 = (g3J3 + g3J3) + av * H33;                                  \
        H00 = n00; H01 = n01; H03 = n03; H11 = n11;                            \
        H12 = n12; H13 = n13; H23 = n23; H33 = n33;                            \
        J0 = (x * dt1) + av * J0;                                              \
        J1 = (h * dt2) + av * J1;                                              \
        J2 = (x * x) + av * J2;                                                \
        J3 = (h * h) + av * J3;                                                \
    }

#define JH_EMIT(qq)  {                                                         \
        *((float4*)(Jout + 4 * (qq))) = make_float4(J0, J1, J2, J3);           \
        float4* Hp = (float4*)(Hout + 16 * (qq));                              \
        Hp[0] = make_float4(H00, H01, 0.0f, H03);                              \
        Hp[1] = make_float4(H01, H11, H12, H13);                               \
        Hp[2] = make_float4(0.0f, H12, 0.0f, H23);                             \
        Hp[3] = make_float4(H03, H13, H23, H33);                               \
    }

#define JH_ZERO(qq)  {                                                         \
        float4 z4 = make_float4(0.f, 0.f, 0.f, 0.f);                           \
        *((float4*)(Jout + 4 * (qq))) = z4;                                    \
        float4* Hp = (float4*)(Hout + 16 * (qq));                              \
        Hp[0] = z4; Hp[1] = z4; Hp[2] = z4; Hp[3] = z4;                        \
    }

    if (a0 > 0) {
        long m0 = q0 - a0 + 1;
        JH_SIMPLE(m0);
        for (long m = m0 + 1; m <= q0; ++m) JH_STEP(m);
    }
    JH_EMIT(q0);
#pragma unroll
    for (int j = 1; j < 4; ++j) {
        int aj = (int)((u >> (8 * j)) & 0xffu);
        long qj = q0 + j;
        if (aj == 0) {
            J0 = J1 = J2 = J3 = 0.0f;
            H00 = H01 = H03 = H11 = H12 = H13 = H23 = H33 = 0.0f;
            JH_ZERO(qj);
        } else if (aj == 1) {
            JH_SIMPLE(qj);
            JH_EMIT(qj);
        } else {
            JH_STEP(qj);
            JH_EMIT(qj);
        }
    }
#undef JH_SIMPLE
#undef JH_STEP
#undef JH_EMIT
#undef JH_ZERO
}

extern "C" void kernel_launch(void* const* d_in, const int* in_sizes, int n_in,
                              void* d_out, int out_size, void* d_ws, size_t ws_size,
                              hipStream_t stream) {
    const float* X = (const float*)d_in[0];
    const float* P = (const float*)d_in[1];
    float* out = (float*)d_out;
    float* Z = out;                       // [T]
    float* Jout = out + (long)TLEN;       // [T,4]
    float* Hout = out + 5l * TLEN;        // [T,4,4]

    char* ws = (char*)d_ws;
    float* consts = (float*)ws;                                    // @0, 64 B
    unsigned int* BT = (unsigned int*)(ws + 64);                   // 64 dwords
    unsigned int* L32 = (unsigned int*)(ws + 512);                 // 128 KB
    unsigned int* age = (unsigned int*)(ws + 512 + (size_t)NSB * 4);   // 1 MB

    hipLaunchKernelGGL(k_hscan, dim3(TLEN / 8 / 256), dim3(256), 0, stream,
                       P, X, consts, Z);
    hipLaunchKernelGGL(k_tabscan, dim3(NSCB), dim3(SCB), 0, stream,
                       consts, Z, L32, BT);
    hipLaunchKernelGGL(k_age, dim3(NSB / 256), dim3(256), 0, stream,
                       consts, Z, L32, BT, age);
    hipLaunchKernelGGL(k_jh, dim3(TLEN / 4 / 256), dim3(256), 0, stream,
                       X, Z, consts, age, Jout, Hout);
}

// Round 12
// 59.701 us; speedup vs baseline: 8.0035x; 1.1116x over previous
//
#include <hip/hip_runtime.h>
#include <math.h>

#define TLEN (1 << 20)
#define SB 32              // reset-chain sub-chunk
#define NSB (TLEN / SB)    // 32768 sub-chunks
#define SCB 512            // maps per scan block
#define NSCB (NSB / SCB)   // 64 scan blocks
#define THRESH 1e-4f
#define IDMAP 0x00FAC688u  // packed identity map: entry g -> g (3 bits each)

#define WWORDS (SCB * SB + 8)      // 16392 staged Z words (8 lead slots)
#define WPAD(i) ((i) + ((i) >> 5)) // +1 word per 32: kills stride-32 bank conflicts
#define LDSW WPAD(WWORDS)

#pragma clang fp contract(off)

// consts layout: 0:w1 1:w2 2:w3 3:w4 4:dt1 5:dt2 6:d2t1 7:d2t2 8:2*w4

// The canonical 32-output chunk program: warm-up 24 + 31 emit steps (55 total).
// EVERY Z value on the device is produced by exactly this program at offset o;
// t==0's lead recompute replays the previous owner's program verbatim -> same bits.
#define CHUNK55(OFS, OUTARR) {                                                 \
        const float4* xp_ = (const float4*)(X + (OFS) - 24);                   \
        float xa_[56];                                                         \
        _Pragma("unroll")                                                      \
        for (int q_ = 0; q_ < 14; ++q_) {                                      \
            float4 v_ = xp_[q_];                                               \
            xa_[4 * q_ + 0] = v_.x; xa_[4 * q_ + 1] = v_.y;                    \
            xa_[4 * q_ + 2] = v_.z; xa_[4 * q_ + 3] = v_.w;                    \
        }                                                                      \
        float h_ = 0.0f;                                                       \
        _Pragma("unroll")                                                      \
        for (int p_ = 0; p_ < 55; ++p_) {                                      \
            float x_ = xa_[p_];                                                \
            float t1_ = w1 * x_;                                               \
            float t2_ = w2 * h_;                                               \
            float s1_ = t1_ + t2_;                                             \
            float t3_ = (w3 * x_) * x_;                                        \
            float s2_ = s1_ + t3_;                                             \
            float t4_ = (w4 * h_) * h_;                                        \
            h_ = s2_ + t4_;                                                    \
            if (p_ >= 23) OUTARR[p_ - 23] = h_;                                \
        }                                                                      \
    }

// K1: Z + tables + scan in one launch. 64 blocks x 512 threads; each thread
// computes its 32-value Z chunk (writes Z AND stages the same registers into
// LDS), t==0 replays the previous owner's chunk for the 7 lead values, then
// round-8-proven map build + Hillis-Steele scan.
__global__ void __launch_bounds__(512) k_zts(const float* __restrict__ P,
                                             const float* __restrict__ X,
                                             float* __restrict__ c,
                                             float* __restrict__ Z,
                                             unsigned int* __restrict__ L32,
                                             unsigned int* __restrict__ BT) {
#pragma clang fp contract(off)
    __shared__ float sc[4];
    __shared__ float zw[LDSW];
    __shared__ unsigned int buf[2][SCB];
    int t = threadIdx.x;
    int b = blockIdx.x;
    if (t == 0) {
        float tw1 = (float)tanh((double)P[0]);
        float tw2 = (float)tanh((double)P[1]);
        sc[0] = tw1; sc[1] = tw2; sc[2] = P[2]; sc[3] = P[3];
        if (b == 0) {
            float dt1 = 1.0f - tw1 * tw1;
            float dt2 = 1.0f - tw2 * tw2;
            c[0] = tw1; c[1] = tw2; c[2] = P[2]; c[3] = P[3];
            c[4] = dt1; c[5] = dt2;
            c[6] = (-2.0f * tw1) * dt1; c[7] = (-2.0f * tw2) * dt2;
            c[8] = 2.0f * P[3];
        }
    }
    __syncthreads();
    float w1 = sc[0], w2 = sc[1], w3 = sc[2], w4 = sc[3];
    float w42 = 2.0f * w4;
    long gi = (long)b * SCB + t;
    long o = gi * 32;
    float out[32];
    if (gi == 0) {
        float h = 0.0f;
        out[0] = 0.0f;                       // Z[0]
        for (int k = 0; k < 31; ++k) {
            float x = X[k];
            float t1 = w1 * x;
            float t2 = w2 * h;
            float s1 = t1 + t2;
            float t3 = (w3 * x) * x;
            float s2 = s1 + t3;
            float t4 = (w4 * h) * h;
            h = s2 + t4;
            out[k + 1] = h;
        }
    } else {
        CHUNK55(o, out);
    }
#pragma unroll
    for (int q = 0; q < 8; ++q)
        *(float4*)(Z + o + 4 * q) = make_float4(out[4 * q], out[4 * q + 1],
                                                out[4 * q + 2], out[4 * q + 3]);
    int rbase = t * 32 + 8;
#pragma unroll
    for (int k = 0; k < 32; ++k) zw[WPAD(rbase + k)] = out[k];
    if (t == 0 && b > 0) {
        long op = (long)b * (SCB * SB) - 32;   // previous chunk owner's offset
        float pout[32];
        CHUNK55(op, pout);
#pragma unroll
        for (int q = 0; q < 7; ++q) zw[WPAD(1 + q)] = pout[25 + q];
    }
    __syncthreads();
    // ---- map build (round-8 proven body, verbatim) ----
    unsigned int m32;
    if (gi < NSB - 1) {
        float d[8]; int last[8];
#pragma unroll
        for (int g = 0; g < 8; ++g) { d[g] = 1.0f; last[g] = -g; }
        if (gi == 0) {
#pragma unroll
            for (int g = 0; g < 8; ++g) last[g] = 0;
            for (int k = 0; k < 32; ++k) {
                float fa = fabsf(w2 + w42 * zw[WPAD(rbase + k)]);
#pragma unroll
                for (int g = 0; g < 8; ++g) {
                    d[g] = d[g] * fa;
                    if (d[g] < THRESH) { last[g] = k + 1; d[g] = 1.0f; }
                }
            }
        } else {
#pragma unroll
            for (int p = 0; p < 7; ++p) {
                float fa = fabsf(w2 + w42 * zw[WPAD(rbase + p - 7)]);
#pragma unroll
                for (int g = 7 - p; g < 8; ++g) {
                    d[g] = d[g] * fa;
                    if (d[g] < THRESH) { last[g] = p - 6; d[g] = 1.0f; }
                }
            }
            for (int k = 0; k < 32; ++k) {
                float fa = fabsf(w2 + w42 * zw[WPAD(rbase + k)]);
#pragma unroll
                for (int g = 0; g < 8; ++g) {
                    d[g] = d[g] * fa;
                    if (d[g] < THRESH) { last[g] = k + 1; d[g] = 1.0f; }
                }
            }
        }
        m32 = 0;
#pragma unroll
        for (int g = 0; g < 8; ++g) {
            int delta = 32 - last[g]; if (delta > 7) delta = 7;
            m32 |= (unsigned int)delta << (3 * g);
        }
    } else {
        m32 = IDMAP;
    }
    // ---- scan (round-8 proven body, verbatim) ----
    buf[0][t] = m32;
    __syncthreads();
    int cur = 0;
    for (int off = 1; off < SCB; off <<= 1) {
        unsigned int hi = buf[cur][t];
        unsigned int r;
        if (t >= off) {
            unsigned int lo = buf[cur][t - off];
            r = 0;
#pragma unroll
            for (int g = 0; g < 8; ++g) {
                unsigned int lg = (lo >> (3 * g)) & 7u;
                r |= ((hi >> (3 * lg)) & 7u) << (3 * g);
            }
        } else {
            r = hi;
        }
        buf[cur ^ 1][t] = r;
        __syncthreads();
        cur ^= 1;
    }
    L32[gi] = buf[cur][t];
    if (t == SCB - 1) BT[b] = buf[cur][t];
}

// K2: age + jh in one launch. Block covers 1024 outputs = 32 sub-chunks.
// Threads 0-31 run the round-8-proven age body into LDS; barrier; all 256
// threads run the round-11-proven jh body (4 outputs each) from LDS ages.
__global__ void __launch_bounds__(256) k_jha(const float* __restrict__ X,
                                             const float* __restrict__ Z,
                                             const float* __restrict__ c,
                                             const unsigned int* __restrict__ L32,
                                             const unsigned int* __restrict__ BT,
                                             float* __restrict__ Jout,
                                             float* __restrict__ Hout) {
#pragma clang fp contract(off)
    __shared__ unsigned int sBT[NSCB];
    __shared__ unsigned int packed[32][8];
    int t = threadIdx.x;
    int B = blockIdx.x;
    float w2 = c[1], dt1 = c[4], dt2 = c[5], d2t1 = c[6], d2t2 = c[7], w42 = c[8];
    if (t < NSCB) sBT[t] = BT[t];
    __syncthreads();
    if (t < 32) {
        int i = B * 32 + t;
        int e = 0;
        if (i > 0) {
            int bp = (i - 1) >> 9;           // / SCB
            unsigned int g = 0;
            for (int k = 0; k < bp; ++k) g = (sBT[k] >> (3 * g)) & 7u;
            e = (int)((L32[i - 1] >> (3 * g)) & 7u);
        }
        long ci = (long)i * SB;
        long r = ci - e;
        float d = 1.0f;
        long last = r;
        for (long m = r + 1; m <= ci; ++m) {
            float a = w2 + w42 * Z[m - 1];
            d = d * fabsf(a);
            if (d < THRESH) { last = m; d = 1.0f; }
        }
        unsigned int cw = (unsigned int)(ci - last);
        int slot = 1, wi = 0;
#pragma unroll
        for (int k = 1; k < SB; ++k) {
            long m = ci + k;
            float a = w2 + w42 * Z[m - 1];
            d = d * fabsf(a);
            if (d < THRESH) { last = m; d = 1.0f; }
            cw |= ((unsigned int)(m - last)) << (8 * slot);
            if (++slot == 4) { packed[t][wi++] = cw; cw = 0u; slot = 0; }
        }
    }
    __syncthreads();
    unsigned int u = packed[t >> 3][t & 7];
    long i4 = (long)B * 256 + t;
    long q0 = 4 * i4;
    int a0 = (int)(u & 0xffu);
    float J0 = 0, J1 = 0, J2 = 0, J3 = 0;
    float H00 = 0, H01 = 0, H03 = 0, H11 = 0, H12 = 0, H13 = 0, H23 = 0, H33 = 0;

#define JH_SIMPLE(mm) {                                                        \
        float x = X[(mm) - 1];                                                 \
        float h = Z[(mm) - 1];                                                 \
        H00 = x * d2t1; H11 = h * d2t2;                                        \
        H01 = 0.0f; H03 = 0.0f; H12 = 0.0f; H13 = 0.0f; H23 = 0.0f; H33 = 0.0f;\
        J0 = x * dt1; J1 = h * dt2; J2 = x * x; J3 = h * h;                    \
    }

#define JH_STEP(mm)  {                                                         \
        float x = X[(mm) - 1];                                                 \
        float h = Z[(mm) - 1];                                                 \
        float av = w2 + w42 * h;                                               \
        float g3 = 2.0f * h;                                                   \
        float g1J0 = dt2 * J0, g1J1 = dt2 * J1, g1J2 = dt2 * J2, g1J3 = dt2 * J3; \
        float g3J0 = g3 * J0, g3J1 = g3 * J1, g3J2 = g3 * J2, g3J3 = g3 * J3;  \
        float n00 = (x * d2t1) + av * H00;                                     \
        float n01 = g1J0 + av * H01;                                           \
        float n03 = g3J0 + av * H03;                                           \
        float n11 = (((h * d2t2) + g1J1) + g1J1) + av * H11;                   \
        float n12 = g1J2 + av * H12;                                           \
        float n13 = (g1J3 + g3J1) + av * H13;                                  \
        float n23 = g3J2 + av * H23;                                           \
        float n33 = (g3J3 + g3J3) + av * H33;                                  \
        H00 = n00; H01 = n01; H03 = n03; H11 = n11;                            \
        H12 = n12; H13 = n13; H23 = n23; H33 = n33;                            \
        J0 = (x * dt1) + av * J0;                                              \
        J1 = (h * dt2) + av * J1;                                              \
        J2 = (x * x) + av * J2;                                                \
        J3 = (h * h) + av * J3;                                                \
    }

#define JH_EMIT(qq)  {                                                         \
        *((float4*)(Jout + 4 * (qq))) = make_float4(J0, J1, J2, J3);           \
        float4* Hp = (float4*)(Hout + 16 * (qq));                              \
        Hp[0] = make_float4(H00, H01, 0.0f, H03);                              \
        Hp[1] = make_float4(H01, H11, H12, H13);                               \
        Hp[2] = make_float4(0.0f, H12, 0.0f, H23);                             \
        Hp[3] = make_float4(H03, H13, H23, H33);                               \
    }

#define JH_ZERO(qq)  {                                                         \
        float4 z4 = make_float4(0.f, 0.f, 0.f, 0.f);                           \
        *((float4*)(Jout + 4 * (qq))) = z4;                                    \
        float4* Hp = (float4*)(Hout + 16 * (qq));                              \
        Hp[0] = z4; Hp[1] = z4; Hp[2] = z4; Hp[3] = z4;                        \
    }

    if (a0 > 0) {
        long m0 = q0 - a0 + 1;
        JH_SIMPLE(m0);
        for (long m = m0 + 1; m <= q0; ++m) JH_STEP(m);
    }
    JH_EMIT(q0);
#pragma unroll
    for (int j = 1; j < 4; ++j) {
        int aj = (int)((u >> (8 * j)) & 0xffu);
        long qj = q0 + j;
        if (aj == 0) {
            J0 = J1 = J2 = J3 = 0.0f;
            H00 = H01 = H03 = H11 = H12 = H13 = H23 = H33 = 0.0f;
            JH_ZERO(qj);
        } else if (aj == 1) {
            JH_SIMPLE(qj);
            JH_EMIT(qj);
        } else {
            JH_STEP(qj);
            JH_EMIT(qj);
        }
    }
#undef JH_SIMPLE
#undef JH_STEP
#undef JH_EMIT
#undef JH_ZERO
}

extern "C" void kernel_launch(void* const* d_in, const int* in_sizes, int n_in,
                              void* d_out, int out_size, void* d_ws, size_t ws_size,
                              hipStream_t stream) {
    const float* X = (const float*)d_in[0];
    const float* P = (const float*)d_in[1];
    float* out = (float*)d_out;
    float* Z = out;                       // [T]
    float* Jout = out + (long)TLEN;       // [T,4]
    float* Hout = out + 5l * TLEN;        // [T,4,4]

    char* ws = (char*)d_ws;
    float* consts = (float*)ws;                                    // @0, 64 B
    unsigned int* BT = (unsigned int*)(ws + 64);                   // 64 dwords
    unsigned int* L32 = (unsigned int*)(ws + 512);                 // 128 KB

    hipLaunchKernelGGL(k_zts, dim3(NSCB), dim3(SCB), 0, stream,
                       P, X, consts, Z, L32, BT);
    hipLaunchKernelGGL(k_jha, dim3(TLEN / 1024), dim3(256), 0, stream,
                       X, Z, consts, L32, BT, Jout, Hout);
}

// Round 13
// 59.088 us; speedup vs baseline: 8.0865x; 1.0104x over previous
//
#include <hip/hip_runtime.h>
#include <math.h>

#define TLEN (1 << 20)
#define SB 32              // reset-chain sub-chunk
#define NSB (TLEN / SB)    // 32768 sub-chunks
#define SCB 512            // maps per scan block
#define NSCB (NSB / SCB)   // 64 scan blocks
#define THRESH 1e-4f
#define IDMAP 0x00FAC688u  // packed identity map: entry g -> g (3 bits each)

#define WWORDS (SCB * SB + 8)      // 16392 staged Z words (8 lead slots)
#define WPAD(i) ((i) + ((i) >> 5)) // +1 word per 32: kills stride-32 bank conflicts
#define LDSW WPAD(WWORDS)

#pragma clang fp contract(off)

// consts layout: 0:w1 1:w2 2:w3 3:w4 4:dt1 5:dt2 6:d2t1 7:d2t2 8:2*w4

// The canonical 32-output chunk program (round-12 PROVEN, verbatim).
#define CHUNK55(OFS, OUTARR) {                                                 \
        const float4* xp_ = (const float4*)(X + (OFS) - 24);                   \
        float xa_[56];                                                         \
        _Pragma("unroll")                                                      \
        for (int q_ = 0; q_ < 14; ++q_) {                                      \
            float4 v_ = xp_[q_];                                               \
            xa_[4 * q_ + 0] = v_.x; xa_[4 * q_ + 1] = v_.y;                    \
            xa_[4 * q_ + 2] = v_.z; xa_[4 * q_ + 3] = v_.w;                    \
        }                                                                      \
        float h_ = 0.0f;                                                       \
        _Pragma("unroll")                                                      \
        for (int p_ = 0; p_ < 55; ++p_) {                                      \
            float x_ = xa_[p_];                                                \
            float t1_ = w1 * x_;                                               \
            float t2_ = w2 * h_;                                               \
            float s1_ = t1_ + t2_;                                             \
            float t3_ = (w3 * x_) * x_;                                        \
            float s2_ = s1_ + t3_;                                             \
            float t4_ = (w4 * h_) * h_;                                        \
            h_ = s2_ + t4_;                                                    \
            if (p_ >= 23) OUTARR[p_ - 23] = h_;                                \
        }                                                                      \
    }

// K1: Z + tables + scan in one launch (round-12 PROVEN, verbatim).
__global__ void __launch_bounds__(512) k_zts(const float* __restrict__ P,
                                             const float* __restrict__ X,
                                             float* __restrict__ c,
                                             float* __restrict__ Z,
                                             unsigned int* __restrict__ L32,
                                             unsigned int* __restrict__ BT) {
#pragma clang fp contract(off)
    __shared__ float sc[4];
    __shared__ float zw[LDSW];
    __shared__ unsigned int buf[2][SCB];
    int t = threadIdx.x;
    int b = blockIdx.x;
    if (t == 0) {
        float tw1 = (float)tanh((double)P[0]);
        float tw2 = (float)tanh((double)P[1]);
        sc[0] = tw1; sc[1] = tw2; sc[2] = P[2]; sc[3] = P[3];
        if (b == 0) {
            float dt1 = 1.0f - tw1 * tw1;
            float dt2 = 1.0f - tw2 * tw2;
            c[0] = tw1; c[1] = tw2; c[2] = P[2]; c[3] = P[3];
            c[4] = dt1; c[5] = dt2;
            c[6] = (-2.0f * tw1) * dt1; c[7] = (-2.0f * tw2) * dt2;
            c[8] = 2.0f * P[3];
        }
    }
    __syncthreads();
    float w1 = sc[0], w2 = sc[1], w3 = sc[2], w4 = sc[3];
    float w42 = 2.0f * w4;
    long gi = (long)b * SCB + t;
    long o = gi * 32;
    float out[32];
    if (gi == 0) {
        float h = 0.0f;
        out[0] = 0.0f;                       // Z[0]
        for (int k = 0; k < 31; ++k) {
            float x = X[k];
            float t1 = w1 * x;
            float t2 = w2 * h;
            float s1 = t1 + t2;
            float t3 = (w3 * x) * x;
            float s2 = s1 + t3;
            float t4 = (w4 * h) * h;
            h = s2 + t4;
            out[k + 1] = h;
        }
    } else {
        CHUNK55(o, out);
    }
#pragma unroll
    for (int q = 0; q < 8; ++q)
        *(float4*)(Z + o + 4 * q) = make_float4(out[4 * q], out[4 * q + 1],
                                                out[4 * q + 2], out[4 * q + 3]);
    int rbase = t * 32 + 8;
#pragma unroll
    for (int k = 0; k < 32; ++k) zw[WPAD(rbase + k)] = out[k];
    if (t == 0 && b > 0) {
        long op = (long)b * (SCB * SB) - 32;   // previous chunk owner's offset
        float pout[32];
        CHUNK55(op, pout);
#pragma unroll
        for (int q = 0; q < 7; ++q) zw[WPAD(1 + q)] = pout[25 + q];
    }
    __syncthreads();
    unsigned int m32;
    if (gi < NSB - 1) {
        float d[8]; int last[8];
#pragma unroll
        for (int g = 0; g < 8; ++g) { d[g] = 1.0f; last[g] = -g; }
        if (gi == 0) {
#pragma unroll
            for (int g = 0; g < 8; ++g) last[g] = 0;
            for (int k = 0; k < 32; ++k) {
                float fa = fabsf(w2 + w42 * zw[WPAD(rbase + k)]);
#pragma unroll
                for (int g = 0; g < 8; ++g) {
                    d[g] = d[g] * fa;
                    if (d[g] < THRESH) { last[g] = k + 1; d[g] = 1.0f; }
                }
            }
        } else {
#pragma unroll
            for (int p = 0; p < 7; ++p) {
                float fa = fabsf(w2 + w42 * zw[WPAD(rbase + p - 7)]);
#pragma unroll
                for (int g = 7 - p; g < 8; ++g) {
                    d[g] = d[g] * fa;
                    if (d[g] < THRESH) { last[g] = p - 6; d[g] = 1.0f; }
                }
            }
            for (int k = 0; k < 32; ++k) {
                float fa = fabsf(w2 + w42 * zw[WPAD(rbase + k)]);
#pragma unroll
                for (int g = 0; g < 8; ++g) {
                    d[g] = d[g] * fa;
                    if (d[g] < THRESH) { last[g] = k + 1; d[g] = 1.0f; }
                }
            }
        }
        m32 = 0;
#pragma unroll
        for (int g = 0; g < 8; ++g) {
            int delta = 32 - last[g]; if (delta > 7) delta = 7;
            m32 |= (unsigned int)delta << (3 * g);
        }
    } else {
        m32 = IDMAP;
    }
    buf[0][t] = m32;
    __syncthreads();
    int cur = 0;
    for (int off = 1; off < SCB; off <<= 1) {
        unsigned int hi = buf[cur][t];
        unsigned int r;
        if (t >= off) {
            unsigned int lo = buf[cur][t - off];
            r = 0;
#pragma unroll
            for (int g = 0; g < 8; ++g) {
                unsigned int lg = (lo >> (3 * g)) & 7u;
                r |= ((hi >> (3 * lg)) & 7u) << (3 * g);
            }
        } else {
            r = hi;
        }
        buf[cur ^ 1][t] = r;
        __syncthreads();
        cur ^= 1;
    }
    L32[gi] = buf[cur][t];
    if (t == SCB - 1) BT[b] = buf[cur][t];
}

// K2: age + jh, ONE output per thread (line-complete stores). Block = 256
// outputs = 8 sub-chunks. Threads 0-7: round-8-proven age replay -> LDS bytes;
// barrier; each thread replays its output's JH chain from its reset (<=7 steps,
// bit-identical to the round-11 induction) and stores J (coalesced float4) and
// H (one 64-B line per output, filled by 4 back-to-back float4 stores).
__global__ void __launch_bounds__(256) k_jh2(const float* __restrict__ X,
                                             const float* __restrict__ Z,
                                             const float* __restrict__ c,
                                             const unsigned int* __restrict__ L32,
                                             const unsigned int* __restrict__ BT,
                                             float* __restrict__ Jout,
                                             float* __restrict__ Hout) {
#pragma clang fp contract(off)
    __shared__ unsigned int sBT[NSCB];
    __shared__ unsigned char ages[256];
    int t = threadIdx.x;
    int B = blockIdx.x;
    float w2 = c[1], dt1 = c[4], dt2 = c[5], d2t1 = c[6], d2t2 = c[7], w42 = c[8];
    if (t < NSCB) sBT[t] = BT[t];
    __syncthreads();
    if (t < 8) {
        int i = B * 8 + t;
        int e = 0;
        if (i > 0) {
            int bp = (i - 1) >> 9;           // / SCB
            unsigned int g = 0;
            for (int k = 0; k < bp; ++k) g = (sBT[k] >> (3 * g)) & 7u;
            e = (int)((L32[i - 1] >> (3 * g)) & 7u);
        }
        long ci = (long)i * SB;
        long r = ci - e;
        float d = 1.0f;
        long last = r;
        for (long m = r + 1; m <= ci; ++m) {
            float a = w2 + w42 * Z[m - 1];
            d = d * fabsf(a);
            if (d < THRESH) { last = m; d = 1.0f; }
        }
        ages[t * 32] = (unsigned char)(ci - last);
        for (int k = 1; k < SB; ++k) {
            long m = ci + k;
            float a = w2 + w42 * Z[m - 1];
            d = d * fabsf(a);
            if (d < THRESH) { last = m; d = 1.0f; }
            ages[t * 32 + k] = (unsigned char)(m - last);
        }
    }
    __syncthreads();
    long q = (long)B * 256 + t;
    int a = (int)ages[t];
    float J0 = 0, J1 = 0, J2 = 0, J3 = 0;
    float H00 = 0, H01 = 0, H03 = 0, H11 = 0, H12 = 0, H13 = 0, H23 = 0, H33 = 0;
    if (a > 0) {
        long m0 = q - a + 1;
        {   // JH_SIMPLE(m0): fresh state after reset
            float x = X[m0 - 1];
            float h = Z[m0 - 1];
            H00 = x * d2t1; H11 = h * d2t2;
            J0 = x * dt1; J1 = h * dt2; J2 = x * x; J3 = h * h;
        }
        for (long m = m0 + 1; m <= q; ++m) {
            float x = X[m - 1];
            float h = Z[m - 1];
            float av = w2 + w42 * h;
            float g3 = 2.0f * h;
            float g1J0 = dt2 * J0, g1J1 = dt2 * J1, g1J2 = dt2 * J2, g1J3 = dt2 * J3;
            float g3J0 = g3 * J0, g3J1 = g3 * J1, g3J2 = g3 * J2, g3J3 = g3 * J3;
            float n00 = (x * d2t1) + av * H00;
            float n01 = g1J0 + av * H01;
            float n03 = g3J0 + av * H03;
            float n11 = (((h * d2t2) + g1J1) + g1J1) + av * H11;
            float n12 = g1J2 + av * H12;
            float n13 = (g1J3 + g3J1) + av * H13;
            float n23 = g3J2 + av * H23;
            float n33 = (g3J3 + g3J3) + av * H33;
            H00 = n00; H01 = n01; H03 = n03; H11 = n11;
            H12 = n12; H13 = n13; H23 = n23; H33 = n33;
            J0 = (x * dt1) + av * J0;
            J1 = (h * dt2) + av * J1;
            J2 = (x * x) + av * J2;
            J3 = (h * h) + av * J3;
        }
    }
    *((float4*)(Jout + 4 * q)) = make_float4(J0, J1, J2, J3);
    float4* Hp = (float4*)(Hout + 16 * q);
    Hp[0] = make_float4(H00, H01, 0.0f, H03);
    Hp[1] = make_float4(H01, H11, H12, H13);
    Hp[2] = make_float4(0.0f, H12, 0.0f, H23);
    Hp[3] = make_float4(H03, H13, H23, H33);
}

extern "C" void kernel_launch(void* const* d_in, const int* in_sizes, int n_in,
                              void* d_out, int out_size, void* d_ws, size_t ws_size,
                              hipStream_t stream) {
    const float* X = (const float*)d_in[0];
    const float* P = (const float*)d_in[1];
    float* out = (float*)d_out;
    float* Z = out;                       // [T]
    float* Jout = out + (long)TLEN;       // [T,4]
    float* Hout = out + 5l * TLEN;        // [T,4,4]

    char* ws = (char*)d_ws;
    float* consts = (float*)ws;                                    // @0, 64 B
    unsigned int* BT = (unsigned int*)(ws + 64);                   // 64 dwords
    unsigned int* L32 = (unsigned int*)(ws + 512);                 // 128 KB

    hipLaunchKernelGGL(k_zts, dim3(NSCB), dim3(SCB), 0, stream,
                       P, X, consts, Z, L32, BT);
    hipLaunchKernelGGL(k_jh2, dim3(TLEN / 256), dim3(256), 0, stream,
                       X, Z, consts, L32, BT, Jout, Hout);
}